// Round 10
// baseline (4955.738 us; speedup 1.0000x reference)
//
#include <hip/hip_runtime.h>
#include <hip/hip_fp16.h>
#include <stdint.h>
#include <stddef.h>

#define Bb 64
#define Ss 1024
#define Ii 512
#define Hh 512
#define G4 2048   // 4*H
#define NBK 32    // recurrence blocks
#define JPB 16    // hidden units per block

typedef _Float16 h16;
typedef _Float16 h16x8 __attribute__((ext_vector_type(8)));
typedef float    f32x4 __attribute__((ext_vector_type(4)));
typedef unsigned u32x4 __attribute__((ext_vector_type(4)));   // native, asm-legal

__device__ __forceinline__ float sigm(float x){ return 1.0f / (1.0f + __expf(-x)); }
__device__ __forceinline__ float tanh_(float x){
  float e = __expf(-2.0f * fabsf(x));
  float t = (1.0f - e) / (1.0f + e);
  return copysignf(t, x);
}

// device-coherent accesses: bypass L1+L2, served at device coherence point
__device__ __forceinline__ u32x4 load_coh16(const void* p){
  u32x4 r;
  asm volatile("global_load_dwordx4 %0, %1, off sc0 sc1"
               : "=v"(r) : "v"(p) : "memory");
  return r;
}
__device__ __forceinline__ void store_coh2(void* p, unsigned v){
  asm volatile("global_store_short %0, %1, off sc0 sc1"
               :: "v"(p), "v"(v) : "memory");
}
// plain 16B load + FULL DRAIN inside the asm: result architecturally complete
// at asm exit -> safe against RA spill placement (prologue-only, cold path).
__device__ __forceinline__ u32x4 load_once16_drain(const void* p){
  u32x4 r;
  asm volatile("global_load_dwordx4 %0, %1, off\n\t"
               "s_waitcnt vmcnt(0)"
               : "=v"(r) : "v"(p) : "memory");
  return r;
}

// h fragment-order offset: h[b][j] -> ((b>>4)*16 + (j>>5))*512
//                                     + ((b&15)|(((j>>3)&3)<<4))*8 + (j&7)
__device__ __forceinline__ int hfrag_off(int b, int j){
  return ((b >> 4) * 16 + (j >> 5)) * 512 + (((b & 15) | (((j >> 3) & 3) << 4)) << 3) + (j & 7);
}

// ---------------------------------------------------------------------------
// prep 1: WxT[n][k] = (f16) W_xh[k][n] for k < I  (B^T layout for gemm_zx)
// ---------------------------------------------------------------------------
__global__ void prep_weights(const float* __restrict__ Wxh, h16* __restrict__ WxT){
  int idx = blockIdx.x * 256 + threadIdx.x;
  if (idx >= Ii * G4) return;
  int k = idx / G4, n = idx % G4;
  WxT[(size_t)n * Ii + k] = (h16)Wxh[idx];
}

// ---------------------------------------------------------------------------
// prep 2: pack W_h into per-block register-fragment order (JPB=16: 64 frags
// per block: frag pk = n*16+ks, n = gate, ks = K-tile) + init both h buffers
// in fragment order. Buffer0 = h0 with tag 0; buffer1 = tag 1 (poison-proof).
// ---------------------------------------------------------------------------
__global__ void prep_rec(const float* __restrict__ Wxh, u32x4* __restrict__ Wr,
                         const float* __restrict__ h0g,
                         unsigned short* __restrict__ hbuf){
  int blk = blockIdx.x, tid = threadIdx.x;
  if (blk < 512){
    int d  = blk * 256 + tid;
    int l  = d & 63, pk = (d >> 6) & 63, bk = d >> 12;
    int n  = pk >> 4, ks = pk & 15;
    int k  = ks * 32 + (l >> 4) * 8;
    int col = n * 512 + bk * JPB + (l & 15);
    h16x8 v;
    #pragma unroll
    for (int e = 0; e < 8; ++e)
      v[e] = (h16)Wxh[(size_t)(Ii + k + e) * G4 + col];
    Wr[d] = *(u32x4*)&v;
  } else {
    int t = (blk - 512) * 256 + tid;    // 0..1023
    #pragma unroll
    for (int i = 0; i < 32; ++i){
      int idx = t * 32 + i;             // idx = b*512 + j
      int b = idx >> 9, j = idx & 511;
      h16 v = (h16)h0g[idx];
      unsigned short bits = *(unsigned short*)&v;
      int off = hfrag_off(b, j);
      hbuf[off]           = (unsigned short)(bits & 0xFFFEu);  // tag 0
      hbuf[Bb * Hh + off] = (unsigned short)0x0001u;           // tag 1
    }
  }
}

// ---------------------------------------------------------------------------
// zx GEMM (unchanged): zx[r][n] = sum_k x_row(r)[k] * W_x[k][n]
// ---------------------------------------------------------------------------
#define BM 128
#define BN 128
#define BK 32
#define LDP 48

__global__ __launch_bounds__(256) void gemm_zx(const float* __restrict__ x,
                                               const h16* __restrict__ WxT,
                                               float* __restrict__ zx,
                                               int t0, int tclog){
  __shared__ h16 lA[BM][LDP];
  __shared__ h16 lB[BN][LDP];
  const int tid  = threadIdx.x;
  const int lane = tid & 63, wid = tid >> 6;
  const int wm = wid >> 1, wn = wid & 1;
  const int bn0 = blockIdx.x * BN, bm0 = blockIdx.y * BM;

  f32x4 acc[4][4] = {};

  const int r_local = tid >> 1;
  const int kh = (tid & 1) * 16;
  const int r = bm0 + r_local;
  const int bidx = r >> tclog;
  const int sc   = r & ((1 << tclog) - 1);
  const float* xrow = x + ((size_t)bidx * Ss + (t0 + sc)) * Ii + kh;

  for (int ks = 0; ks < Ii / BK; ++ks){
    const int k0 = ks * BK;
    __syncthreads();
    {
      const float* p = xrow + k0;
      f32x4 v0 = *(const f32x4*)(p);
      f32x4 v1 = *(const f32x4*)(p + 4);
      f32x4 v2 = *(const f32x4*)(p + 8);
      f32x4 v3 = *(const f32x4*)(p + 12);
      h16x8 o0, o1;
      o0[0]=(h16)v0[0]; o0[1]=(h16)v0[1]; o0[2]=(h16)v0[2]; o0[3]=(h16)v0[3];
      o0[4]=(h16)v1[0]; o0[5]=(h16)v1[1]; o0[6]=(h16)v1[2]; o0[7]=(h16)v1[3];
      o1[0]=(h16)v2[0]; o1[1]=(h16)v2[1]; o1[2]=(h16)v2[2]; o1[3]=(h16)v2[3];
      o1[4]=(h16)v3[0]; o1[5]=(h16)v3[1]; o1[6]=(h16)v3[2]; o1[7]=(h16)v3[3];
      *(h16x8*)&lA[r_local][kh]     = o0;
      *(h16x8*)&lA[r_local][kh + 8] = o1;
    }
    #pragma unroll
    for (int i = 0; i < 2; ++i){
      int flat = i * 256 + tid;
      int nl = flat >> 2, kq = flat & 3;
      u32x4 w = *(const u32x4*)(WxT + ((size_t)(bn0 + nl)) * Ii + k0 + kq * 8);
      *(u32x4*)&lB[nl][kq * 8] = w;
    }
    __syncthreads();
    h16x8 af[4], bfr[4];
    #pragma unroll
    for (int m = 0; m < 4; ++m)
      af[m] = *(const h16x8*)&lA[wm * 64 + m * 16 + (lane & 15)][(lane >> 4) * 8];
    #pragma unroll
    for (int n = 0; n < 4; ++n)
      bfr[n] = *(const h16x8*)&lB[wn * 64 + n * 16 + (lane & 15)][(lane >> 4) * 8];
    #pragma unroll
    for (int m = 0; m < 4; ++m)
      #pragma unroll
      for (int n = 0; n < 4; ++n)
        acc[m][n] = __builtin_amdgcn_mfma_f32_16x16x32_f16(af[m], bfr[n], acc[m][n], 0, 0, 0);
  }
  #pragma unroll
  for (int m = 0; m < 4; ++m){
    int rg = bm0 + wm * 64 + m * 16 + ((lane >> 4) << 2);
    #pragma unroll
    for (int n = 0; n < 4; ++n){
      int cg = bn0 + wn * 64 + n * 16 + (lane & 15);
      #pragma unroll
      for (int q = 0; q < 4; ++q)
        zx[(size_t)(rg + q) * G4 + cg] = acc[m][n][q];
    }
  }
}

// ---------------------------------------------------------------------------
// Recurrence v8: JPB=16, gates lane-local, free-run, tag-LSB validation.
// Spill-hazard hardened: hr declared in-loop and consumed in the SAME basic
// block right after vmcnt(0) (R6/R7-verified shape); weight prologue drains
// per-load so bfr defs are complete at asm exit.
// ---------------------------------------------------------------------------
__global__ __launch_bounds__(256, 1) void lstm_rec2(
    const float* __restrict__ zx, const u32x4* __restrict__ Wr,
    unsigned short* __restrict__ hbuf,
    const float* __restrict__ c0g, float* __restrict__ c_state,
    const float* __restrict__ Wci, const float* __restrict__ Wcf, const float* __restrict__ Wco,
    const float* __restrict__ bi, const float* __restrict__ bfg, const float* __restrict__ bc,
    const float* __restrict__ bo,
    float* __restrict__ out, float* __restrict__ hT, float* __restrict__ cT,
    int t0, int Tc, int first, int last)
{
  const int bk = blockIdx.x, tid = threadIdx.x;
  const int l = tid & 63, w = tid >> 6;
  const int j15 = l & 15;            // j-local
  const int p4  = l >> 4;            // 0..3
  const int jg  = bk * JPB + j15;    // global j
  const int bbase = w * 16 + p4 * 4; // lane's 4 batches: bbase+q

  const float wci = Wci[jg], wcf = Wcf[jg], wco = Wco[jg];
  const float vbi = bi[jg], vbf = bfg[jg], vbc = bc[jg], vbo = bo[jg];

  float cst[4];
  #pragma unroll
  for (int q = 0; q < 4; ++q)
    cst[q] = first ? c0g[(bbase + q) * Hh + jg] : c_state[(bbase + q) * Hh + jg];

  // --- W_h fragments: 64 frags, each load fully drained inside its asm ---
  h16x8 bfr[64];
  {
    const u32x4* p = Wr + (size_t)bk * 4096 + l;
    #pragma unroll
    for (int pk = 0; pk < 64; ++pk){
      u32x4 t = load_once16_drain(p + (size_t)pk * 64);
      bfr[pk] = *(h16x8*)&t;
    }
  }

  // --- zx per-lane addressing: row pointers for the 4 batches ---
  const float* zp[4];
  #pragma unroll
  for (int q = 0; q < 4; ++q)
    zp[q] = zx + (size_t)(bbase + q) * Tc * G4 + jg;

  float zc[16];
  #pragma unroll
  for (int q = 0; q < 4; ++q)
    #pragma unroll
    for (int n = 0; n < 4; ++n)
      zc[q * 4 + n] = zp[q][n * 512];

  const int ld_base = w * 8192 + l * 8;
  const int soff0 = (w * 16 + (bk >> 1)) * 512
                  + (((p4 << 2)) | ((((bk << 1) + (j15 >> 3)) & 3) << 4)) * 8 + (l & 7);

  for (int s = 0; s < Tc; ++s){
    const int gs = t0 + s;
    const int par = gs & 1;

    // prefetch next step's zx (clamped index: always initialized, in-bounds)
    const int sn = (s + 1 < Tc) ? (s + 1) : s;
    float zn[16];
    #pragma unroll
    for (int q = 0; q < 4; ++q)
      #pragma unroll
      for (int n = 0; n < 4; ++n)
        zn[q * 4 + n] = zp[q][(size_t)sn * G4 + n * 512];

    // --- fused retry volley: load + validate + MFMA in ONE basic block ---
    const unsigned exp32 = (((unsigned)gs >> 1) & 1u) * 0x00010001u;
    const unsigned short* hp = hbuf + (size_t)par * (Bb * Hh) + ld_base;
    f32x4 a0, a1, a2, a3;
    for (;;){
      u32x4 hr[16];
      #pragma unroll
      for (int pk = 0; pk < 16; ++pk)
        hr[pk] = load_coh16(hp + pk * 512);
      asm volatile("s_waitcnt vmcnt(0)" ::: "memory");
      __builtin_amdgcn_sched_barrier(0);
      unsigned bad = 0;
      a0 = (f32x4){0.f,0.f,0.f,0.f};
      a1 = (f32x4){0.f,0.f,0.f,0.f};
      a2 = (f32x4){0.f,0.f,0.f,0.f};
      a3 = (f32x4){0.f,0.f,0.f,0.f};
      #pragma unroll
      for (int pk = 0; pk < 16; ++pk){
        u32x4 v = hr[pk];
        bad |= (v[0] ^ exp32) & 0x00010001u;
        bad |= (v[1] ^ exp32) & 0x00010001u;
        bad |= (v[2] ^ exp32) & 0x00010001u;
        bad |= (v[3] ^ exp32) & 0x00010001u;
        h16x8 a = *(h16x8*)&v;
        a0 = __builtin_amdgcn_mfma_f32_16x16x32_f16(a, bfr[pk],      a0, 0, 0, 0);
        a1 = __builtin_amdgcn_mfma_f32_16x16x32_f16(a, bfr[16 + pk], a1, 0, 0, 0);
        a2 = __builtin_amdgcn_mfma_f32_16x16x32_f16(a, bfr[32 + pk], a2, 0, 0, 0);
        a3 = __builtin_amdgcn_mfma_f32_16x16x32_f16(a, bfr[48 + pk], a3, 0, 0, 0);
      }
      if (__all(bad == 0)) break;
    }

    // --- gates fully in-register; coherent h store with tag LSB ---
    const unsigned tagn = (((unsigned)(gs + 1) >> 1) & 1u);
    unsigned short* hdst = hbuf + (size_t)(par ^ 1) * (Bb * Hh) + soff0;
    #pragma unroll
    for (int q = 0; q < 4; ++q){
      const int b = bbase + q;
      float z_i = a0[q] + zc[q * 4 + 0];
      float z_f = a1[q] + zc[q * 4 + 1];
      float z_c = a2[q] + zc[q * 4 + 2];
      float z_o = a3[q] + zc[q * 4 + 3];
      float cp = cst[q];
      float iv = sigm(z_i + cp * wci + vbi);
      float fv = sigm(z_f + cp * wcf + vbf);
      float cn = fv * cp + iv * tanh_(z_c + vbc);
      float ov = sigm(z_o + cn * wco + vbo);
      float hn = ov * tanh_(cn);
      cst[q] = cn;
      h16 hh = (h16)hn;
      unsigned hbits = ((unsigned)*(unsigned short*)&hh & 0xFFFEu) | tagn;
      store_coh2(hdst + q * 8, hbits);
      out[((size_t)b * Ss + gs) * Hh + jg] = hn;
      if (last && s == Tc - 1){ hT[b * Hh + jg] = hn; cT[b * Hh + jg] = cn; }
    }

    #pragma unroll
    for (int i = 0; i < 16; ++i) zc[i] = zn[i];
  }

  #pragma unroll
  for (int q = 0; q < 4; ++q)
    c_state[(bbase + q) * Hh + jg] = cst[q];
}

// ---------------------------------------------------------------------------
extern "C" void kernel_launch(void* const* d_in, const int* in_sizes, int n_in,
                              void* d_out, int out_size, void* d_ws, size_t ws_size,
                              hipStream_t stream){
  const float* x   = (const float*)d_in[0];
  const float* h0  = (const float*)d_in[1];
  const float* c0  = (const float*)d_in[2];
  const float* Wxh = (const float*)d_in[3];
  const float* Wci = (const float*)d_in[4];
  const float* Wcf = (const float*)d_in[5];
  const float* Wco = (const float*)d_in[6];
  const float* bi  = (const float*)d_in[7];
  const float* bf  = (const float*)d_in[8];
  const float* bc  = (const float*)d_in[9];
  const float* bo  = (const float*)d_in[10];

  float* out = (float*)d_out;
  float* hT  = out + (size_t)Bb * Ss * Hh;
  float* cT  = hT + (size_t)Bb * Hh;

  uint8_t* ws = (uint8_t*)d_ws;
  size_t off = 0;
  auto take = [&](size_t bytes) -> uint8_t* {
    uint8_t* p = ws + off;
    off += (bytes + 255) & ~(size_t)255;
    return p;
  };
  h16*            WxT     = (h16*)take((size_t)G4 * Ii * 2);
  u32x4*          Wr      = (u32x4*)take((size_t)G4 * Hh * 2);
  unsigned short* hbuf    = (unsigned short*)take((size_t)2 * Bb * Hh * 2);
  float*          c_state = (float*)take((size_t)Bb * Hh * 4);

  int Tc = Ss, tclog = 10;
  while (Tc > 2 && off + (size_t)Bb * Tc * G4 * 4 > ws_size){ Tc >>= 1; tclog--; }
  float* zxbuf = (float*)take((size_t)Bb * Tc * G4 * 4);

  prep_weights<<<(Ii * G4) / 256, 256, 0, stream>>>(Wxh, WxT);
  prep_rec<<<516, 256, 0, stream>>>(Wxh, Wr, h0, hbuf);

  int nch = Ss / Tc;
  for (int c = 0; c < nch; ++c){
    int t0 = c * Tc;
    dim3 grid(G4 / BN, Bb * Tc / BM);
    gemm_zx<<<grid, 256, 0, stream>>>(x, WxT, zxbuf, t0, tclog);
    lstm_rec2<<<NBK, 256, 0, stream>>>(zxbuf, Wr, hbuf, c0, c_state,
                                       Wci, Wcf, Wco, bi, bf, bc, bo,
                                       out, hT, cT, t0, Tc, c == 0, c == nch - 1);
  }
}

// Round 11
// 4313.052 us; speedup vs baseline: 1.1490x; 1.1490x over previous
//
#include <hip/hip_runtime.h>
#include <hip/hip_fp16.h>
#include <stdint.h>
#include <stddef.h>

#define Bb 64
#define Ss 1024
#define Ii 512
#define Hh 512
#define G4 2048   // 4*H
#define NBK 64    // recurrence blocks
#define JPB 8     // hidden units per block

typedef _Float16 h16;
typedef _Float16 h16x8 __attribute__((ext_vector_type(8)));
typedef float    f32x4 __attribute__((ext_vector_type(4)));
typedef unsigned u32x4 __attribute__((ext_vector_type(4)));   // native, asm-legal

__device__ __forceinline__ float sigm(float x){ return 1.0f / (1.0f + __expf(-x)); }
__device__ __forceinline__ float tanh_(float x){
  float e = __expf(-2.0f * fabsf(x));
  float t = (1.0f - e) / (1.0f + e);
  return copysignf(t, x);
}

// device-coherent accesses: bypass L1+L2, served at device coherence point
__device__ __forceinline__ u32x4 load_coh16(const void* p){
  u32x4 r;
  asm volatile("global_load_dwordx4 %0, %1, off sc0 sc1"
               : "=v"(r) : "v"(p) : "memory");
  return r;
}
__device__ __forceinline__ void store_coh2(void* p, unsigned v){
  asm volatile("global_store_short %0, %1, off sc0 sc1"
               :: "v"(p), "v"(v) : "memory");
}
// plain 16B load + FULL DRAIN inside the asm: result architecturally complete
// at asm exit -> safe against RA spill placement (prologue-only, cold path).
__device__ __forceinline__ u32x4 load_once16_drain(const void* p){
  u32x4 r;
  asm volatile("global_load_dwordx4 %0, %1, off\n\t"
               "s_waitcnt vmcnt(0)"
               : "=v"(r) : "v"(p) : "memory");
  return r;
}

// h fragment-order offset: h[b][j] -> ((b>>4)*16 + (j>>5))*512
//                                     + ((b&15)|(((j>>3)&3)<<4))*8 + (j&7)
__device__ __forceinline__ int hfrag_off(int b, int j){
  return ((b >> 4) * 16 + (j >> 5)) * 512 + (((b & 15) | (((j >> 3) & 3) << 4)) << 3) + (j & 7);
}

// ---------------------------------------------------------------------------
// prep 1: WxT[n][k] = (f16) W_xh[k][n] for k < I  (B^T layout for gemm_zx)
// ---------------------------------------------------------------------------
__global__ void prep_weights(const float* __restrict__ Wxh, h16* __restrict__ WxT){
  int idx = blockIdx.x * 256 + threadIdx.x;
  if (idx >= Ii * G4) return;
  int k = idx / G4, n = idx % G4;
  WxT[(size_t)n * Ii + k] = (h16)Wxh[idx];
}

// ---------------------------------------------------------------------------
// prep 2: pack W_h into per-block register-fragment order (JPB=8, 32 frags:
// pk = n*16+ks, n-frag covers cols cl = n*16+(l&15): gate = cl>>3, j = cl&7)
// + init both h buffers in fragment order (tag 0 / tag 1).
// ---------------------------------------------------------------------------
__global__ void prep_rec(const float* __restrict__ Wxh, u32x4* __restrict__ Wr,
                         const float* __restrict__ h0g,
                         unsigned short* __restrict__ hbuf){
  int blk = blockIdx.x, tid = threadIdx.x;
  if (blk < 512){
    int d  = blk * 256 + tid;
    int l  = d & 63, pk = (d >> 6) & 31, bk = d >> 11;
    int n  = pk >> 4, ks = pk & 15;
    int k  = ks * 32 + (l >> 4) * 8;
    int cl = n * 16 + (l & 15);
    int col = (cl >> 3) * 512 + bk * JPB + (cl & 7);
    h16x8 v;
    #pragma unroll
    for (int e = 0; e < 8; ++e)
      v[e] = (h16)Wxh[(size_t)(Ii + k + e) * G4 + col];
    Wr[d] = *(u32x4*)&v;
  } else {
    int t = (blk - 512) * 256 + tid;    // 0..1023
    #pragma unroll
    for (int i = 0; i < 32; ++i){
      int idx = t * 32 + i;             // idx = b*512 + j
      int b = idx >> 9, j = idx & 511;
      h16 v = (h16)h0g[idx];
      unsigned short bits = *(unsigned short*)&v;
      int off = hfrag_off(b, j);
      hbuf[off]           = (unsigned short)(bits & 0xFFFEu);  // tag 0
      hbuf[Bb * Hh + off] = (unsigned short)0x0001u;           // tag 1
    }
  }
}

// ---------------------------------------------------------------------------
// zx GEMM (unchanged): zx[r][n] = sum_k x_row(r)[k] * W_x[k][n]
// ---------------------------------------------------------------------------
#define BM 128
#define BN 128
#define BK 32
#define LDP 48

__global__ __launch_bounds__(256) void gemm_zx(const float* __restrict__ x,
                                               const h16* __restrict__ WxT,
                                               float* __restrict__ zx,
                                               int t0, int tclog){
  __shared__ h16 lA[BM][LDP];
  __shared__ h16 lB[BN][LDP];
  const int tid  = threadIdx.x;
  const int lane = tid & 63, wid = tid >> 6;
  const int wm = wid >> 1, wn = wid & 1;
  const int bn0 = blockIdx.x * BN, bm0 = blockIdx.y * BM;

  f32x4 acc[4][4] = {};

  const int r_local = tid >> 1;
  const int kh = (tid & 1) * 16;
  const int r = bm0 + r_local;
  const int bidx = r >> tclog;
  const int sc   = r & ((1 << tclog) - 1);
  const float* xrow = x + ((size_t)bidx * Ss + (t0 + sc)) * Ii + kh;

  for (int ks = 0; ks < Ii / BK; ++ks){
    const int k0 = ks * BK;
    __syncthreads();
    {
      const float* p = xrow + k0;
      f32x4 v0 = *(const f32x4*)(p);
      f32x4 v1 = *(const f32x4*)(p + 4);
      f32x4 v2 = *(const f32x4*)(p + 8);
      f32x4 v3 = *(const f32x4*)(p + 12);
      h16x8 o0, o1;
      o0[0]=(h16)v0[0]; o0[1]=(h16)v0[1]; o0[2]=(h16)v0[2]; o0[3]=(h16)v0[3];
      o0[4]=(h16)v1[0]; o0[5]=(h16)v1[1]; o0[6]=(h16)v1[2]; o0[7]=(h16)v1[3];
      o1[0]=(h16)v2[0]; o1[1]=(h16)v2[1]; o1[2]=(h16)v2[2]; o1[3]=(h16)v2[3];
      o1[4]=(h16)v3[0]; o1[5]=(h16)v3[1]; o1[6]=(h16)v3[2]; o1[7]=(h16)v3[3];
      *(h16x8*)&lA[r_local][kh]     = o0;
      *(h16x8*)&lA[r_local][kh + 8] = o1;
    }
    #pragma unroll
    for (int i = 0; i < 2; ++i){
      int flat = i * 256 + tid;
      int nl = flat >> 2, kq = flat & 3;
      u32x4 w = *(const u32x4*)(WxT + ((size_t)(bn0 + nl)) * Ii + k0 + kq * 8);
      *(u32x4*)&lB[nl][kq * 8] = w;
    }
    __syncthreads();
    h16x8 af[4], bfr[4];
    #pragma unroll
    for (int m = 0; m < 4; ++m)
      af[m] = *(const h16x8*)&lA[wm * 64 + m * 16 + (lane & 15)][(lane >> 4) * 8];
    #pragma unroll
    for (int n = 0; n < 4; ++n)
      bfr[n] = *(const h16x8*)&lB[wn * 64 + n * 16 + (lane & 15)][(lane >> 4) * 8];
    #pragma unroll
    for (int m = 0; m < 4; ++m)
      #pragma unroll
      for (int n = 0; n < 4; ++n)
        acc[m][n] = __builtin_amdgcn_mfma_f32_16x16x32_f16(af[m], bfr[n], acc[m][n], 0, 0, 0);
  }
  #pragma unroll
  for (int m = 0; m < 4; ++m){
    int rg = bm0 + wm * 64 + m * 16 + ((lane >> 4) << 2);
    #pragma unroll
    for (int n = 0; n < 4; ++n){
      int cg = bn0 + wn * 64 + n * 16 + (lane & 15);
      #pragma unroll
      for (int q = 0; q < 4; ++q)
        zx[(size_t)(rg + q) * G4 + cg] = acc[m][n][q];
    }
  }
}

// ---------------------------------------------------------------------------
// Recurrence v9: R7 skeleton (64 blocks, JPB=8, fragment-order h, tag-LSB
// validation, fused spill-safe volley) with the LDS gate exchange replaced
// by two __shfl_xor(.,8) (lane l has gates {i,c}, lane l^8 has {f,o} for the
// SAME (b,j)). Gates + c-state lane-resident; one barrier/step (phase align).
// ---------------------------------------------------------------------------
__global__ __launch_bounds__(256, 1) void lstm_rec2(
    const float* __restrict__ zx, const u32x4* __restrict__ Wr,
    unsigned short* __restrict__ hbuf,
    const float* __restrict__ c0g, float* __restrict__ c_state,
    const float* __restrict__ Wci, const float* __restrict__ Wcf, const float* __restrict__ Wco,
    const float* __restrict__ bi, const float* __restrict__ bfg, const float* __restrict__ bc,
    const float* __restrict__ bo,
    float* __restrict__ out, float* __restrict__ hT, float* __restrict__ cT,
    int t0, int Tc, int first, int last)
{
  const int bk = blockIdx.x, tid = threadIdx.x;
  const int l = tid & 63, w = tid >> 6;
  const int lq = l >> 4;                 // 0..3
  const int jg = bk * JPB + (l & 7);     // this lane's j
  const bool lowhalf = (l & 8) == 0;     // holds {i,c}; l^8 holds {f,o}

  const float wci = Wci[jg], wcf = Wcf[jg], wco = Wco[jg];
  const float vbi = bi[jg], vbf = bfg[jg], vbc = bc[jg], vbo = bo[jg];

  float cst[4];
  #pragma unroll
  for (int q = 0; q < 4; ++q){
    const int b = w * 16 + lq * 4 + q;
    cst[q] = first ? c0g[b * Hh + jg] : c_state[b * Hh + jg];
  }

  // --- W_h fragments: 32 frags (128 regs), drained per-load (spill-safe) ---
  h16x8 bfr[32];
  {
    const u32x4* p = Wr + (size_t)bk * 2048 + l;
    #pragma unroll
    for (int pk = 0; pk < 32; ++pk){
      u32x4 t = load_once16_drain(p + (size_t)pk * 64);
      bfr[pk] = *(h16x8*)&t;
    }
  }

  // --- zx per-lane: 16 values/step (4 batches x 4 gates), prefetched ---
  const float* zp[4];
  #pragma unroll
  for (int q = 0; q < 4; ++q)
    zp[q] = zx + (size_t)(w * 16 + lq * 4 + q) * Tc * G4 + jg;

  float zc[16];
  #pragma unroll
  for (int q = 0; q < 4; ++q)
    #pragma unroll
    for (int g = 0; g < 4; ++g)
      zc[q * 4 + g] = zp[q][g * 512];

  const int ld_base = w * 8192 + l * 8;
  // producer store offset: b = w*16+lq*4+q, j = jg ->
  //  off = (w*16 + bk>>2)*512 + ((lq*4+q)|((bk&3)<<4))*8 + (l&7)
  const int soff_base = (w * 16 + (bk >> 2)) * 512
                      + (((lq * 4) | ((bk & 3) << 4)) << 3) + (l & 7);

  for (int s = 0; s < Tc; ++s){
    const int gs = t0 + s;
    const int par = gs & 1;

    // prefetch next step's zx (clamped: always initialized, in-bounds)
    const int sn = (s + 1 < Tc) ? (s + 1) : s;
    float zn[16];
    #pragma unroll
    for (int q = 0; q < 4; ++q)
      #pragma unroll
      for (int g = 0; g < 4; ++g)
        zn[q * 4 + g] = zp[q][(size_t)sn * G4 + g * 512];

    // --- fused retry volley (one BB): load + validate + MFMA, halves ---
    const unsigned exp32 = (((unsigned)gs >> 1) & 1u) * 0x00010001u;
    const unsigned short* hp = hbuf + (size_t)par * (Bb * Hh) + ld_base;
    f32x4 a0, a1;
    for (;;){
      u32x4 hr[16];
      #pragma unroll
      for (int pk = 0; pk < 16; ++pk)
        hr[pk] = load_coh16(hp + pk * 512);
      unsigned bad = 0;
      a0 = (f32x4){0.f,0.f,0.f,0.f};
      a1 = (f32x4){0.f,0.f,0.f,0.f};
      asm volatile("s_waitcnt vmcnt(8)" ::: "memory");
      __builtin_amdgcn_sched_barrier(0);
      #pragma unroll
      for (int pk = 0; pk < 8; ++pk){
        u32x4 v = hr[pk];
        bad |= (v[0] ^ exp32) & 0x00010001u;
        bad |= (v[1] ^ exp32) & 0x00010001u;
        bad |= (v[2] ^ exp32) & 0x00010001u;
        bad |= (v[3] ^ exp32) & 0x00010001u;
        h16x8 a = *(h16x8*)&v;
        a0 = __builtin_amdgcn_mfma_f32_16x16x32_f16(a, bfr[pk],      a0, 0, 0, 0);
        a1 = __builtin_amdgcn_mfma_f32_16x16x32_f16(a, bfr[16 + pk], a1, 0, 0, 0);
      }
      asm volatile("s_waitcnt vmcnt(0)" ::: "memory");
      __builtin_amdgcn_sched_barrier(0);
      #pragma unroll
      for (int pk = 8; pk < 16; ++pk){
        u32x4 v = hr[pk];
        bad |= (v[0] ^ exp32) & 0x00010001u;
        bad |= (v[1] ^ exp32) & 0x00010001u;
        bad |= (v[2] ^ exp32) & 0x00010001u;
        bad |= (v[3] ^ exp32) & 0x00010001u;
        h16x8 a = *(h16x8*)&v;
        a0 = __builtin_amdgcn_mfma_f32_16x16x32_f16(a, bfr[pk],      a0, 0, 0, 0);
        a1 = __builtin_amdgcn_mfma_f32_16x16x32_f16(a, bfr[16 + pk], a1, 0, 0, 0);
      }
      if (__all(bad == 0)) break;
    }

    // --- in-wave gate exchange: lane l <-> l^8 ---
    f32x4 e0, e1;
    #pragma unroll
    for (int c = 0; c < 4; ++c){
      e0[c] = __shfl_xor(a0[c], 8);
      e1[c] = __shfl_xor(a1[c], 8);
    }

    const unsigned tagn = (((unsigned)(gs + 1) >> 1) & 1u);
    unsigned short* hdst = hbuf + (size_t)(par ^ 1) * (Bb * Hh) + soff_base;
    float hn4[4];
    #pragma unroll
    for (int q = 0; q < 4; ++q){
      float z_i = (lowhalf ? a0[q] : e0[q]) + zc[q * 4 + 0];
      float z_f = (lowhalf ? e0[q] : a0[q]) + zc[q * 4 + 1];
      float z_c = (lowhalf ? a1[q] : e1[q]) + zc[q * 4 + 2];
      float z_o = (lowhalf ? e1[q] : a1[q]) + zc[q * 4 + 3];
      float cp = cst[q];
      float iv = sigm(z_i + cp * wci + vbi);
      float fv = sigm(z_f + cp * wcf + vbf);
      float cn = fv * cp + iv * tanh_(z_c + vbc);
      float ov = sigm(z_o + cn * wco + vbo);
      float hn = ov * tanh_(cn);
      cst[q] = cn; hn4[q] = hn;
      if (lowhalf){
        h16 hh = (h16)hn;
        unsigned hbits = ((unsigned)*(unsigned short*)&hh & 0xFFFEu) | tagn;
        store_coh2(hdst + q * 8, hbits);       // critical path: h first
      }
    }
    if (lowhalf){
      #pragma unroll
      for (int q = 0; q < 4; ++q){
        const int b = w * 16 + lq * 4 + q;
        out[((size_t)b * Ss + gs) * Hh + jg] = hn4[q];
        if (last && s == Tc - 1){ hT[b * Hh + jg] = hn4[q]; cT[b * Hh + jg] = cst[q]; }
      }
    }

    __syncthreads();   // phase aligner (drains stores before next volley)

    #pragma unroll
    for (int i = 0; i < 16; ++i) zc[i] = zn[i];
  }

  if (lowhalf){
    #pragma unroll
    for (int q = 0; q < 4; ++q)
      c_state[(w * 16 + lq * 4 + q) * Hh + jg] = cst[q];
  }
}

// ---------------------------------------------------------------------------
extern "C" void kernel_launch(void* const* d_in, const int* in_sizes, int n_in,
                              void* d_out, int out_size, void* d_ws, size_t ws_size,
                              hipStream_t stream){
  const float* x   = (const float*)d_in[0];
  const float* h0  = (const float*)d_in[1];
  const float* c0  = (const float*)d_in[2];
  const float* Wxh = (const float*)d_in[3];
  const float* Wci = (const float*)d_in[4];
  const float* Wcf = (const float*)d_in[5];
  const float* Wco = (const float*)d_in[6];
  const float* bi  = (const float*)d_in[7];
  const float* bf  = (const float*)d_in[8];
  const float* bc  = (const float*)d_in[9];
  const float* bo  = (const float*)d_in[10];

  float* out = (float*)d_out;
  float* hT  = out + (size_t)Bb * Ss * Hh;
  float* cT  = hT + (size_t)Bb * Hh;

  uint8_t* ws = (uint8_t*)d_ws;
  size_t off = 0;
  auto take = [&](size_t bytes) -> uint8_t* {
    uint8_t* p = ws + off;
    off += (bytes + 255) & ~(size_t)255;
    return p;
  };
  h16*            WxT     = (h16*)take((size_t)G4 * Ii * 2);
  u32x4*          Wr      = (u32x4*)take((size_t)G4 * Hh * 2);
  unsigned short* hbuf    = (unsigned short*)take((size_t)2 * Bb * Hh * 2);
  float*          c_state = (float*)take((size_t)Bb * Hh * 4);

  int Tc = Ss, tclog = 10;
  while (Tc > 2 && off + (size_t)Bb * Tc * G4 * 4 > ws_size){ Tc >>= 1; tclog--; }
  float* zxbuf = (float*)take((size_t)Bb * Tc * G4 * 4);

  prep_weights<<<(Ii * G4) / 256, 256, 0, stream>>>(Wxh, WxT);
  prep_rec<<<516, 256, 0, stream>>>(Wxh, Wr, h0, hbuf);

  int nch = Ss / Tc;
  for (int c = 0; c < nch; ++c){
    int t0 = c * Tc;
    dim3 grid(G4 / BN, Bb * Tc / BM);
    gemm_zx<<<grid, 256, 0, stream>>>(x, WxT, zxbuf, t0, tclog);
    lstm_rec2<<<NBK, 256, 0, stream>>>(zxbuf, Wr, hbuf, c0, c_state,
                                       Wci, Wcf, Wco, bi, bf, bc, bo,
                                       out, hT, cT, t0, Tc, c == 0, c == nch - 1);
  }
}

// Round 12
// 4189.057 us; speedup vs baseline: 1.1830x; 1.0296x over previous
//
#include <hip/hip_runtime.h>
#include <hip/hip_fp16.h>
#include <stdint.h>
#include <stddef.h>

#define Bb 64
#define Ss 1024
#define Ii 512
#define Hh 512
#define G4 2048   // 4*H
#define NBK 64    // recurrence blocks
#define JPB 8     // hidden units per block

typedef _Float16 h16;
typedef _Float16 h16x8 __attribute__((ext_vector_type(8)));
typedef float    f32x4 __attribute__((ext_vector_type(4)));
typedef unsigned u32x4 __attribute__((ext_vector_type(4)));   // native, asm-legal

__device__ __forceinline__ float sigm(float x){ return 1.0f / (1.0f + __expf(-x)); }
__device__ __forceinline__ float tanh_(float x){
  float e = __expf(-2.0f * fabsf(x));
  float t = (1.0f - e) / (1.0f + e);
  return copysignf(t, x);
}

// device-coherent accesses: bypass L1+L2, served at device coherence point
__device__ __forceinline__ u32x4 load_coh16(const void* p){
  u32x4 r;
  asm volatile("global_load_dwordx4 %0, %1, off sc0 sc1"
               : "=v"(r) : "v"(p) : "memory");
  return r;
}
__device__ __forceinline__ void store_coh2(void* p, unsigned v){
  asm volatile("global_store_short %0, %1, off sc0 sc1"
               :: "v"(p), "v"(v) : "memory");
}
// plain 16B load + FULL DRAIN inside the asm: result architecturally complete
// at asm exit -> safe against RA spill placement (prologue-only, cold path).
__device__ __forceinline__ u32x4 load_once16_drain(const void* p){
  u32x4 r;
  asm volatile("global_load_dwordx4 %0, %1, off\n\t"
               "s_waitcnt vmcnt(0)"
               : "=v"(r) : "v"(p) : "memory");
  return r;
}

// h fragment-order offset: h[b][j] -> ((b>>4)*16 + (j>>5))*512
//                                     + ((b&15)|(((j>>3)&3)<<4))*8 + (j&7)
__device__ __forceinline__ int hfrag_off(int b, int j){
  return ((b >> 4) * 16 + (j >> 5)) * 512 + (((b & 15) | (((j >> 3) & 3) << 4)) << 3) + (j & 7);
}

// ---------------------------------------------------------------------------
// prep 1: WxT[n][k] = (f16) W_xh[k][n] for k < I  (B^T layout for gemm_zx)
// ---------------------------------------------------------------------------
__global__ void prep_weights(const float* __restrict__ Wxh, h16* __restrict__ WxT){
  int idx = blockIdx.x * 256 + threadIdx.x;
  if (idx >= Ii * G4) return;
  int k = idx / G4, n = idx % G4;
  WxT[(size_t)n * Ii + k] = (h16)Wxh[idx];
}

// ---------------------------------------------------------------------------
// prep 2: pack W_h into per-block register-fragment order (JPB=8, 32 frags:
// pk = n*16+ks, n-frag covers cols cl = n*16+(l&15): gate = cl>>3, j = cl&7)
// + init both h buffers in fragment order (tag 0 / tag 1).
// ---------------------------------------------------------------------------
__global__ void prep_rec(const float* __restrict__ Wxh, u32x4* __restrict__ Wr,
                         const float* __restrict__ h0g,
                         unsigned short* __restrict__ hbuf){
  int blk = blockIdx.x, tid = threadIdx.x;
  if (blk < 512){
    int d  = blk * 256 + tid;
    int l  = d & 63, pk = (d >> 6) & 31, bk = d >> 11;
    int n  = pk >> 4, ks = pk & 15;
    int k  = ks * 32 + (l >> 4) * 8;
    int cl = n * 16 + (l & 15);
    int col = (cl >> 3) * 512 + bk * JPB + (cl & 7);
    h16x8 v;
    #pragma unroll
    for (int e = 0; e < 8; ++e)
      v[e] = (h16)Wxh[(size_t)(Ii + k + e) * G4 + col];
    Wr[d] = *(u32x4*)&v;
  } else {
    int t = (blk - 512) * 256 + tid;    // 0..1023
    #pragma unroll
    for (int i = 0; i < 32; ++i){
      int idx = t * 32 + i;             // idx = b*512 + j
      int b = idx >> 9, j = idx & 511;
      h16 v = (h16)h0g[idx];
      unsigned short bits = *(unsigned short*)&v;
      int off = hfrag_off(b, j);
      hbuf[off]           = (unsigned short)(bits & 0xFFFEu);  // tag 0
      hbuf[Bb * Hh + off] = (unsigned short)0x0001u;           // tag 1
    }
  }
}

// ---------------------------------------------------------------------------
// zx GEMM (unchanged): zx[r][n] = sum_k x_row(r)[k] * W_x[k][n]
// ---------------------------------------------------------------------------
#define BM 128
#define BN 128
#define BK 32
#define LDP 48

__global__ __launch_bounds__(256) void gemm_zx(const float* __restrict__ x,
                                               const h16* __restrict__ WxT,
                                               float* __restrict__ zx,
                                               int t0, int tclog){
  __shared__ h16 lA[BM][LDP];
  __shared__ h16 lB[BN][LDP];
  const int tid  = threadIdx.x;
  const int lane = tid & 63, wid = tid >> 6;
  const int wm = wid >> 1, wn = wid & 1;
  const int bn0 = blockIdx.x * BN, bm0 = blockIdx.y * BM;

  f32x4 acc[4][4] = {};

  const int r_local = tid >> 1;
  const int kh = (tid & 1) * 16;
  const int r = bm0 + r_local;
  const int bidx = r >> tclog;
  const int sc   = r & ((1 << tclog) - 1);
  const float* xrow = x + ((size_t)bidx * Ss + (t0 + sc)) * Ii + kh;

  for (int ks = 0; ks < Ii / BK; ++ks){
    const int k0 = ks * BK;
    __syncthreads();
    {
      const float* p = xrow + k0;
      f32x4 v0 = *(const f32x4*)(p);
      f32x4 v1 = *(const f32x4*)(p + 4);
      f32x4 v2 = *(const f32x4*)(p + 8);
      f32x4 v3 = *(const f32x4*)(p + 12);
      h16x8 o0, o1;
      o0[0]=(h16)v0[0]; o0[1]=(h16)v0[1]; o0[2]=(h16)v0[2]; o0[3]=(h16)v0[3];
      o0[4]=(h16)v1[0]; o0[5]=(h16)v1[1]; o0[6]=(h16)v1[2]; o0[7]=(h16)v1[3];
      o1[0]=(h16)v2[0]; o1[1]=(h16)v2[1]; o1[2]=(h16)v2[2]; o1[3]=(h16)v2[3];
      o1[4]=(h16)v3[0]; o1[5]=(h16)v3[1]; o1[6]=(h16)v3[2]; o1[7]=(h16)v3[3];
      *(h16x8*)&lA[r_local][kh]     = o0;
      *(h16x8*)&lA[r_local][kh + 8] = o1;
    }
    #pragma unroll
    for (int i = 0; i < 2; ++i){
      int flat = i * 256 + tid;
      int nl = flat >> 2, kq = flat & 3;
      u32x4 w = *(const u32x4*)(WxT + ((size_t)(bn0 + nl)) * Ii + k0 + kq * 8);
      *(u32x4*)&lB[nl][kq * 8] = w;
    }
    __syncthreads();
    h16x8 af[4], bfr[4];
    #pragma unroll
    for (int m = 0; m < 4; ++m)
      af[m] = *(const h16x8*)&lA[wm * 64 + m * 16 + (lane & 15)][(lane >> 4) * 8];
    #pragma unroll
    for (int n = 0; n < 4; ++n)
      bfr[n] = *(const h16x8*)&lB[wn * 64 + n * 16 + (lane & 15)][(lane >> 4) * 8];
    #pragma unroll
    for (int m = 0; m < 4; ++m)
      #pragma unroll
      for (int n = 0; n < 4; ++n)
        acc[m][n] = __builtin_amdgcn_mfma_f32_16x16x32_f16(af[m], bfr[n], acc[m][n], 0, 0, 0);
  }
  #pragma unroll
  for (int m = 0; m < 4; ++m){
    int rg = bm0 + wm * 64 + m * 16 + ((lane >> 4) << 2);
    #pragma unroll
    for (int n = 0; n < 4; ++n){
      int cg = bn0 + wn * 64 + n * 16 + (lane & 15);
      #pragma unroll
      for (int q = 0; q < 4; ++q)
        zx[(size_t)(rg + q) * G4 + cg] = acc[m][n][q];
    }
  }
}

// ---------------------------------------------------------------------------
// Recurrence v10: R7 skeleton (LDS gate exchange, float4 zx staging, fused
// spill-safe tag-volley) but with thread->(b,j) remapped WAVE-LOCAL:
// wave w owns batches [16w,16w+16) end-to-end (MFMA rows, zf/szp rows, gates,
// h-stores). LDS exchange needs only in-wave DS ordering (lgkmcnt) -> ZERO
// barriers; waves free-run. Safety: each wave-index subgroup {wave w of all
// blocks} is a closed producer/consumer ring, so the mod-4 tag induction
// holds per subgroup; cross-subgroup regions are disjoint.
// ---------------------------------------------------------------------------
__global__ __launch_bounds__(256, 1) void lstm_rec2(
    const float* __restrict__ zx, const u32x4* __restrict__ Wr,
    unsigned short* __restrict__ hbuf,
    const float* __restrict__ c0g, float* __restrict__ c_state,
    const float* __restrict__ Wci, const float* __restrict__ Wcf, const float* __restrict__ Wco,
    const float* __restrict__ bi, const float* __restrict__ bfg, const float* __restrict__ bc,
    const float* __restrict__ bo,
    float* __restrict__ out, float* __restrict__ hT, float* __restrict__ cT,
    int t0, int Tc, int first, int last)
{
  __shared__ float zf[4][16][33];    // [wave][batch-local][gate-col]
  __shared__ float szp[4][16][36];   // [wave][batch-local][gate*8+jl]

  const int bk = blockIdx.x, tid = threadIdx.x;
  const int l = tid & 63, w = tid >> 6;
  const int jl = l & 7, bh = l >> 3;         // reader coords
  const int jg = bk * JPB + jl;
  const int bA = w * 16 + bh, bB = bA + 8;   // this thread's two batches

  const float wci = Wci[jg], wcf = Wcf[jg], wco = Wco[jg];
  const float vbi = bi[jg], vbf = bfg[jg], vbc = bc[jg], vbo = bo[jg];

  float cA, cB;
  if (first){ cA = c0g[bA * Hh + jg]; cB = c0g[bB * Hh + jg]; }
  else      { cA = c_state[bA * Hh + jg]; cB = c_state[bB * Hh + jg]; }

  // --- W_h fragments: 32 frags (128 regs), drained per-load (spill-safe) ---
  h16x8 bfr[32];
  {
    const u32x4* p = Wr + (size_t)bk * 2048 + l;
    #pragma unroll
    for (int pk = 0; pk < 32; ++pk){
      u32x4 t = load_once16_drain(p + (size_t)pk * 64);
      bfr[pk] = *(h16x8*)&t;
    }
  }

  // --- zx staging (float4, wave-local): lane stages batch w*16+(l>>2) ---
  const int bz = l >> 2, gz = l & 3;
  const float* zxbase = zx + (size_t)(w * 16 + bz) * Tc * G4 + gz * 512 + bk * JPB;
  float4 zc0 = *(const float4*)(zxbase);
  float4 zc1 = *(const float4*)(zxbase + 4);

  const int ld_base = w * 8192 + l * 8;
  const int crow = (l >> 4) * 4;             // MFMA C local row base
  // producer store offsets (fragment order), b = bA / bB, j = jg
  const int soffA = (w * 16 + (bk >> 2)) * 512 + ((bh      | ((bk & 3) << 4)) << 3) + jl;
  const int soffB = (w * 16 + (bk >> 2)) * 512 + (((8 + bh)| ((bk & 3) << 4)) << 3) + jl;

  for (int s = 0; s < Tc; ++s){
    const int gs = t0 + s;
    const int par = gs & 1;

    // prefetch next step's zx (clamped: always initialized, in-bounds)
    const int sn = (s + 1 < Tc) ? (s + 1) : s;
    float4 zn0, zn1;
    {
      const float* p = zxbase + (size_t)sn * G4;
      zn0 = *(const float4*)p; zn1 = *(const float4*)(p + 4);
    }

    // stage zx into LDS (wave-local; prior reads complete in-order)
    *(float4*)&szp[w][bz][gz * 8]     = zc0;
    *(float4*)&szp[w][bz][gz * 8 + 4] = zc1;

    // --- fused retry volley (one BB): load + validate + MFMA, split halves ---
    const unsigned exp32 = (((unsigned)gs >> 1) & 1u) * 0x00010001u;
    const unsigned short* hp = hbuf + (size_t)par * (Bb * Hh) + ld_base;
    f32x4 a0, a1;
    for (;;){
      u32x4 hr[16];
      #pragma unroll
      for (int pk = 0; pk < 16; ++pk)
        hr[pk] = load_coh16(hp + pk * 512);
      unsigned bad = 0;
      a0 = (f32x4){0.f,0.f,0.f,0.f};
      a1 = (f32x4){0.f,0.f,0.f,0.f};
      asm volatile("s_waitcnt vmcnt(8)" ::: "memory");
      __builtin_amdgcn_sched_barrier(0);
      #pragma unroll
      for (int pk = 0; pk < 8; ++pk){
        u32x4 v = hr[pk];
        bad |= (v[0] ^ exp32) & 0x00010001u;
        bad |= (v[1] ^ exp32) & 0x00010001u;
        bad |= (v[2] ^ exp32) & 0x00010001u;
        bad |= (v[3] ^ exp32) & 0x00010001u;
        h16x8 a = *(h16x8*)&v;
        a0 = __builtin_amdgcn_mfma_f32_16x16x32_f16(a, bfr[pk],      a0, 0, 0, 0);
        a1 = __builtin_amdgcn_mfma_f32_16x16x32_f16(a, bfr[16 + pk], a1, 0, 0, 0);
      }
      asm volatile("s_waitcnt vmcnt(0)" ::: "memory");
      __builtin_amdgcn_sched_barrier(0);
      #pragma unroll
      for (int pk = 8; pk < 16; ++pk){
        u32x4 v = hr[pk];
        bad |= (v[0] ^ exp32) & 0x00010001u;
        bad |= (v[1] ^ exp32) & 0x00010001u;
        bad |= (v[2] ^ exp32) & 0x00010001u;
        bad |= (v[3] ^ exp32) & 0x00010001u;
        h16x8 a = *(h16x8*)&v;
        a0 = __builtin_amdgcn_mfma_f32_16x16x32_f16(a, bfr[pk],      a0, 0, 0, 0);
        a1 = __builtin_amdgcn_mfma_f32_16x16x32_f16(a, bfr[16 + pk], a1, 0, 0, 0);
      }
      if (__all(bad == 0)) break;
    }

    // z partials -> wave-local LDS (C layout: row=crow+q, col=l&15 / 16+)
    #pragma unroll
    for (int q = 0; q < 4; ++q){
      zf[w][crow + q][(l & 15)]      = a0[q];
      zf[w][crow + q][16 + (l & 15)] = a1[q];
    }
    asm volatile("s_waitcnt lgkmcnt(0)" ::: "memory");   // in-wave DS order
    __builtin_amdgcn_sched_barrier(0);

    // gates for (bA,row bh) and (bB,row 8+bh); h stored coherent first
    const unsigned tagn = (((unsigned)(gs + 1) >> 1) & 1u);
    unsigned short* hdst = hbuf + (size_t)(par ^ 1) * (Bb * Hh);
    float hnA, hnB;
    #pragma unroll
    for (int pr = 0; pr < 2; ++pr){
      const int row = pr ? (8 + bh) : bh;
      float cp = pr ? cB : cA;
      float z_i = szp[w][row][jl]      + zf[w][row][jl];
      float z_f = szp[w][row][8 + jl]  + zf[w][row][8 + jl];
      float z_c = szp[w][row][16 + jl] + zf[w][row][16 + jl];
      float z_o = szp[w][row][24 + jl] + zf[w][row][24 + jl];
      float iv = sigm(z_i + cp * wci + vbi);
      float fv = sigm(z_f + cp * wcf + vbf);
      float cn = fv * cp + iv * tanh_(z_c + vbc);
      float ov = sigm(z_o + cn * wco + vbo);
      float hn = ov * tanh_(cn);
      h16 hh = (h16)hn;
      unsigned hbits = ((unsigned)*(unsigned short*)&hh & 0xFFFEu) | tagn;
      store_coh2(hdst + (pr ? soffB : soffA), hbits);    // critical path first
      if (pr){ cB = cn; hnB = hn; } else { cA = cn; hnA = hn; }
    }
    out[((size_t)bA * Ss + gs) * Hh + jg] = hnA;
    out[((size_t)bB * Ss + gs) * Hh + jg] = hnB;
    if (last && s == Tc - 1){
      hT[bA * Hh + jg] = hnA; cT[bA * Hh + jg] = cA;
      hT[bB * Hh + jg] = hnB; cT[bB * Hh + jg] = cB;
    }

    zc0 = zn0; zc1 = zn1;
  }

  c_state[bA * Hh + jg] = cA;
  c_state[bB * Hh + jg] = cB;
}

// ---------------------------------------------------------------------------
extern "C" void kernel_launch(void* const* d_in, const int* in_sizes, int n_in,
                              void* d_out, int out_size, void* d_ws, size_t ws_size,
                              hipStream_t stream){
  const float* x   = (const float*)d_in[0];
  const float* h0  = (const float*)d_in[1];
  const float* c0  = (const float*)d_in[2];
  const float* Wxh = (const float*)d_in[3];
  const float* Wci = (const float*)d_in[4];
  const float* Wcf = (const float*)d_in[5];
  const float* Wco = (const float*)d_in[6];
  const float* bi  = (const float*)d_in[7];
  const float* bf  = (const float*)d_in[8];
  const float* bc  = (const float*)d_in[9];
  const float* bo  = (const float*)d_in[10];

  float* out = (float*)d_out;
  float* hT  = out + (size_t)Bb * Ss * Hh;
  float* cT  = hT + (size_t)Bb * Hh;

  uint8_t* ws = (uint8_t*)d_ws;
  size_t off = 0;
  auto take = [&](size_t bytes) -> uint8_t* {
    uint8_t* p = ws + off;
    off += (bytes + 255) & ~(size_t)255;
    return p;
  };
  h16*            WxT     = (h16*)take((size_t)G4 * Ii * 2);
  u32x4*          Wr      = (u32x4*)take((size_t)G4 * Hh * 2);
  unsigned short* hbuf    = (unsigned short*)take((size_t)2 * Bb * Hh * 2);
  float*          c_state = (float*)take((size_t)Bb * Hh * 4);

  int Tc = Ss, tclog = 10;
  while (Tc > 2 && off + (size_t)Bb * Tc * G4 * 4 > ws_size){ Tc >>= 1; tclog--; }
  float* zxbuf = (float*)take((size_t)Bb * Tc * G4 * 4);

  prep_weights<<<(Ii * G4) / 256, 256, 0, stream>>>(Wxh, WxT);
  prep_rec<<<516, 256, 0, stream>>>(Wxh, Wr, h0, hbuf);

  int nch = Ss / Tc;
  for (int c = 0; c < nch; ++c){
    int t0 = c * Tc;
    dim3 grid(G4 / BN, Bb * Tc / BM);
    gemm_zx<<<grid, 256, 0, stream>>>(x, WxT, zxbuf, t0, tclog);
    lstm_rec2<<<NBK, 256, 0, stream>>>(zxbuf, Wr, hbuf, c0, c_state,
                                       Wci, Wcf, Wco, bi, bf, bc, bo,
                                       out, hT, cT, t0, Tc, c == 0, c == nch - 1);
  }
}

// Round 13
// 2912.790 us; speedup vs baseline: 1.7014x; 1.4382x over previous
//
#include <hip/hip_runtime.h>
#include <hip/hip_fp16.h>
#include <stdint.h>
#include <stddef.h>

#define Bb 64
#define Ss 1024
#define Ii 512
#define Hh 512
#define G4 2048   // 4*H
#define NBK 64    // recurrence blocks (4 groups x 16)

typedef _Float16 h16;
typedef _Float16 h16x8 __attribute__((ext_vector_type(8)));
typedef float    f32x4 __attribute__((ext_vector_type(4)));
typedef unsigned u32x4 __attribute__((ext_vector_type(4)));   // native, asm-legal

__device__ __forceinline__ float sigm(float x){ return 1.0f / (1.0f + __expf(-x)); }
__device__ __forceinline__ float tanh_(float x){
  float e = __expf(-2.0f * fabsf(x));
  float t = (1.0f - e) / (1.0f + e);
  return copysignf(t, x);
}

// device-coherent accesses: bypass L1+L2, served at device coherence point
__device__ __forceinline__ u32x4 load_coh16(const void* p){
  u32x4 r;
  asm volatile("global_load_dwordx4 %0, %1, off sc0 sc1"
               : "=v"(r) : "v"(p) : "memory");
  return r;
}
__device__ __forceinline__ void store_coh2(void* p, unsigned v){
  asm volatile("global_store_short %0, %1, off sc0 sc1"
               :: "v"(p), "v"(v) : "memory");
}
// plain 16B load + FULL DRAIN inside the asm (prologue-only, spill-safe)
__device__ __forceinline__ u32x4 load_once16_drain(const void* p){
  u32x4 r;
  asm volatile("global_load_dwordx4 %0, %1, off\n\t"
               "s_waitcnt vmcnt(0)"
               : "=v"(r) : "v"(p) : "memory");
  return r;
}

// group-h fragment offset: h[b_local][k] ->
//   (k>>5)*512 + ((k>>3)&3)*128 + b_local*8 + (k&7)
__device__ __forceinline__ int ghoff(int bl, int k){
  return (k >> 5) * 512 + ((k >> 3) & 3) * 128 + bl * 8 + (k & 7);
}

// ---------------------------------------------------------------------------
// prep 1: WxT[n][k] = (f16) W_xh[k][n] for k < I  (B^T layout for gemm_zx)
// ---------------------------------------------------------------------------
__global__ void prep_weights(const float* __restrict__ Wxh, h16* __restrict__ WxT){
  int idx = blockIdx.x * 256 + threadIdx.x;
  if (idx >= Ii * G4) return;
  int k = idx / G4, n = idx % G4;
  WxT[(size_t)n * Ii + k] = (h16)Wxh[idx];
}

// ---------------------------------------------------------------------------
// prep 2: pack W_h into per-chunk register-fragment order (chunk cc = 0..63
// owns j in [cc*8, cc*8+8); 32 frags pk = n*16+ks; frag col cl = n*16+(l&15):
// gate = cl>>3, j = cc*8 + (cl&7)) + init the 4 group h buffers (16 batches x
// 512 k each, fragment order): parity0 = h0 (tag 0), parity1 = 0x0001.
// ---------------------------------------------------------------------------
__global__ void prep_rec(const float* __restrict__ Wxh, u32x4* __restrict__ Wr,
                         const float* __restrict__ h0g,
                         unsigned short* __restrict__ hbuf){
  int blk = blockIdx.x, tid = threadIdx.x;
  if (blk < 512){
    int d  = blk * 256 + tid;
    int l  = d & 63, pk = (d >> 6) & 31, cc = d >> 11;
    int n  = pk >> 4, ks = pk & 15;
    int k  = ks * 32 + (l >> 4) * 8;
    int cl = n * 16 + (l & 15);
    int col = (cl >> 3) * 512 + cc * 8 + (cl & 7);
    h16x8 v;
    #pragma unroll
    for (int e = 0; e < 8; ++e)
      v[e] = (h16)Wxh[(size_t)(Ii + k + e) * G4 + col];
    Wr[d] = *(u32x4*)&v;
  } else {
    int t = (blk - 512) * 256 + tid;    // 0..1023
    #pragma unroll
    for (int i = 0; i < 32; ++i){
      int idx = t * 32 + i;             // idx = b*512 + k
      int b = idx >> 9, k = idx & 511;
      int g = b >> 4, bl = b & 15;
      h16 v = (h16)h0g[idx];
      unsigned short bits = *(unsigned short*)&v;
      int off = ghoff(bl, k);
      hbuf[(size_t)(g * 2) * 8192 + off]     = (unsigned short)(bits & 0xFFFEu);
      hbuf[(size_t)(g * 2 + 1) * 8192 + off] = (unsigned short)0x0001u;
    }
  }
}

// ---------------------------------------------------------------------------
// zx GEMM (unchanged): zx[r][n] = sum_k x_row(r)[k] * W_x[k][n]
// ---------------------------------------------------------------------------
#define BM 128
#define BN 128
#define BK 32
#define LDP 48

__global__ __launch_bounds__(256) void gemm_zx(const float* __restrict__ x,
                                               const h16* __restrict__ WxT,
                                               float* __restrict__ zx,
                                               int t0, int tclog){
  __shared__ h16 lA[BM][LDP];
  __shared__ h16 lB[BN][LDP];
  const int tid  = threadIdx.x;
  const int lane = tid & 63, wid = tid >> 6;
  const int wm = wid >> 1, wn = wid & 1;
  const int bn0 = blockIdx.x * BN, bm0 = blockIdx.y * BM;

  f32x4 acc[4][4] = {};

  const int r_local = tid >> 1;
  const int kh = (tid & 1) * 16;
  const int r = bm0 + r_local;
  const int bidx = r >> tclog;
  const int sc   = r & ((1 << tclog) - 1);
  const float* xrow = x + ((size_t)bidx * Ss + (t0 + sc)) * Ii + kh;

  for (int ks = 0; ks < Ii / BK; ++ks){
    const int k0 = ks * BK;
    __syncthreads();
    {
      const float* p = xrow + k0;
      f32x4 v0 = *(const f32x4*)(p);
      f32x4 v1 = *(const f32x4*)(p + 4);
      f32x4 v2 = *(const f32x4*)(p + 8);
      f32x4 v3 = *(const f32x4*)(p + 12);
      h16x8 o0, o1;
      o0[0]=(h16)v0[0]; o0[1]=(h16)v0[1]; o0[2]=(h16)v0[2]; o0[3]=(h16)v0[3];
      o0[4]=(h16)v1[0]; o0[5]=(h16)v1[1]; o0[6]=(h16)v1[2]; o0[7]=(h16)v1[3];
      o1[0]=(h16)v2[0]; o1[1]=(h16)v2[1]; o1[2]=(h16)v2[2]; o1[3]=(h16)v2[3];
      o1[4]=(h16)v3[0]; o1[5]=(h16)v3[1]; o1[6]=(h16)v3[2]; o1[7]=(h16)v3[3];
      *(h16x8*)&lA[r_local][kh]     = o0;
      *(h16x8*)&lA[r_local][kh + 8] = o1;
    }
    #pragma unroll
    for (int i = 0; i < 2; ++i){
      int flat = i * 256 + tid;
      int nl = flat >> 2, kq = flat & 3;
      u32x4 w = *(const u32x4*)(WxT + ((size_t)(bn0 + nl)) * Ii + k0 + kq * 8);
      *(u32x4*)&lB[nl][kq * 8] = w;
    }
    __syncthreads();
    h16x8 af[4], bfr[4];
    #pragma unroll
    for (int m = 0; m < 4; ++m)
      af[m] = *(const h16x8*)&lA[wm * 64 + m * 16 + (lane & 15)][(lane >> 4) * 8];
    #pragma unroll
    for (int n = 0; n < 4; ++n)
      bfr[n] = *(const h16x8*)&lB[wn * 64 + n * 16 + (lane & 15)][(lane >> 4) * 8];
    #pragma unroll
    for (int m = 0; m < 4; ++m)
      #pragma unroll
      for (int n = 0; n < 4; ++n)
        acc[m][n] = __builtin_amdgcn_mfma_f32_16x16x32_f16(af[m], bfr[n], acc[m][n], 0, 0, 0);
  }
  #pragma unroll
  for (int m = 0; m < 4; ++m){
    int rg = bm0 + wm * 64 + m * 16 + ((lane >> 4) << 2);
    #pragma unroll
    for (int n = 0; n < 4; ++n){
      int cg = bn0 + wn * 64 + n * 16 + (lane & 15);
      #pragma unroll
      for (int q = 0; q < 4; ++q)
        zx[(size_t)(rg + q) * G4 + cg] = acc[m][n][q];
    }
  }
}

// ---------------------------------------------------------------------------
// Recurrence v11: 4 independent 16-block batch-group rings. Group g owns
// batches [16g,16g+16); each wave is one j-chunk (8 j's, bfr[32] weights).
// Per step: each wave coherently loads+validates a 4KB share of the group's
// 16KB h tile, stages to double-buffered LDS, ONE barrier, A-frags from LDS,
// 32 MFMAs, wave-local gate exchange, coherent tag-stores. Coherent read
// traffic: 1MB/step total (4x less than R7/R12); sync domain 16 blocks.
// ---------------------------------------------------------------------------
__global__ __launch_bounds__(256, 1) void lstm_rec2(
    const float* __restrict__ zx, const u32x4* __restrict__ Wr,
    unsigned short* __restrict__ hbuf,
    const float* __restrict__ c0g, float* __restrict__ c_state,
    const float* __restrict__ Wci, const float* __restrict__ Wcf, const float* __restrict__ Wco,
    const float* __restrict__ bi, const float* __restrict__ bfg, const float* __restrict__ bc,
    const float* __restrict__ bo,
    float* __restrict__ out, float* __restrict__ hT, float* __restrict__ cT,
    int t0, int Tc, int first, int last)
{
  __shared__ h16   hstage[2][8192];   // group h tile, parity double-buffered
  __shared__ float zf[4][16][33];     // per-wave gate partials
  __shared__ float szp[4][16][36];    // per-wave zx staging

  const int bk = blockIdx.x, tid = threadIdx.x;
  const int l = tid & 63, w = tid >> 6;
  const int g = bk >> 4, i = bk & 15;
  const int cc = i * 4 + w;                 // this wave's j-chunk (0..63)
  const int jl = l & 7;
  const int jg = cc * 8 + jl;               // this thread's j
  const int bl = l >> 3;                    // batch-local 0..7
  const int bgA = g * 16 + bl, bgB = bgA + 8;

  const float wci = Wci[jg], wcf = Wcf[jg], wco = Wco[jg];
  const float vbi = bi[jg], vbf = bfg[jg], vbc = bc[jg], vbo = bo[jg];

  float cA, cB;
  if (first){ cA = c0g[bgA * Hh + jg]; cB = c0g[bgB * Hh + jg]; }
  else      { cA = c_state[bgA * Hh + jg]; cB = c_state[bgB * Hh + jg]; }

  // --- W_h fragments for chunk cc: 32 frags (128 regs), spill-safe loads ---
  h16x8 bfr[32];
  {
    const u32x4* p = Wr + (size_t)cc * 2048 + l;
    #pragma unroll
    for (int pk = 0; pk < 32; ++pk){
      u32x4 t = load_once16_drain(p + (size_t)pk * 64);
      bfr[pk] = *(h16x8*)&t;
    }
  }

  // --- zx staging: thread stages batch bz (0..15), gate gz, chunk cc's 8 j ---
  const int bz = l >> 2, gz = l & 3;
  const float* zxbase = zx + (size_t)(g * 16 + bz) * Tc * G4 + gz * 512 + cc * 8;
  float4 zc0 = *(const float4*)(zxbase);
  float4 zc1 = *(const float4*)(zxbase + 4);

  const int vbase = (l >> 4) * 128 + (l & 15) * 8;   // volley lane offset
  const int soff  = (cc >> 2) * 512 + (cc & 3) * 128; // producer store base
  const int crow  = (l >> 4) * 4;                     // MFMA C local row base

  unsigned short* const hg0 = hbuf + (size_t)(g * 2) * 8192;

  for (int s = 0; s < Tc; ++s){
    const int gs = t0 + s;
    const int par = gs & 1;

    // prefetch next step's zx (clamped: always initialized, in-bounds)
    const int sn = (s + 1 < Tc) ? (s + 1) : s;
    float4 zn0, zn1;
    {
      const float* p = zxbase + (size_t)sn * G4;
      zn0 = *(const float4*)p; zn1 = *(const float4*)(p + 4);
    }

    // stage zx into wave-local LDS
    *(float4*)&szp[w][bz][gz * 8]     = zc0;
    *(float4*)&szp[w][bz][gz * 8 + 4] = zc1;

    // --- own-share volley: 4 coherent loads + tag validate, retry ---
    const unsigned exp32 = (((unsigned)gs >> 1) & 1u) * 0x00010001u;
    const unsigned short* hb = (unsigned short*)hg0 + (size_t)par * 8192;
    u32x4 sh[4];
    for (;;){
      #pragma unroll
      for (int t = 0; t < 4; ++t)
        sh[t] = load_coh16(hb + (w * 4 + t) * 512 + vbase);
      asm volatile("s_waitcnt vmcnt(0)" ::: "memory");
      __builtin_amdgcn_sched_barrier(0);
      unsigned bad = 0;
      #pragma unroll
      for (int t = 0; t < 4; ++t){
        u32x4 v = sh[t];
        bad |= (v[0] ^ exp32) & 0x00010001u;
        bad |= (v[1] ^ exp32) & 0x00010001u;
        bad |= (v[2] ^ exp32) & 0x00010001u;
        bad |= (v[3] ^ exp32) & 0x00010001u;
      }
      if (__all(bad == 0)) break;
    }
    // stage validated share into LDS
    #pragma unroll
    for (int t = 0; t < 4; ++t)
      *(u32x4*)&hstage[par][(w * 4 + t) * 512 + vbase] = sh[t];
    __syncthreads();   // all shares staged AND all waves validated

    // --- A-frags from LDS + 32 MFMAs ---
    f32x4 a0 = {0.f,0.f,0.f,0.f}, a1 = {0.f,0.f,0.f,0.f};
    #pragma unroll
    for (int pk = 0; pk < 16; ++pk){
      h16x8 a = *(const h16x8*)&hstage[par][pk * 512 + vbase];
      a0 = __builtin_amdgcn_mfma_f32_16x16x32_f16(a, bfr[pk],      a0, 0, 0, 0);
      a1 = __builtin_amdgcn_mfma_f32_16x16x32_f16(a, bfr[16 + pk], a1, 0, 0, 0);
    }

    // z partials -> wave-local LDS (C layout: row=crow+q, col=l&15 / 16+)
    #pragma unroll
    for (int q = 0; q < 4; ++q){
      zf[w][crow + q][(l & 15)]      = a0[q];
      zf[w][crow + q][16 + (l & 15)] = a1[q];
    }
    asm volatile("s_waitcnt lgkmcnt(0)" ::: "memory");
    __builtin_amdgcn_sched_barrier(0);

    // gates for (bgA,row bl) and (bgB,row 8+bl); coherent tag-store first
    const unsigned tagn = (((unsigned)(gs + 1) >> 1) & 1u);
    unsigned short* hdst = hg0 + (size_t)(par ^ 1) * 8192 + soff;
    float hnA, hnB;
    #pragma unroll
    for (int pr = 0; pr < 2; ++pr){
      const int row = pr ? (8 + bl) : bl;
      float cp = pr ? cB : cA;
      float z_i = szp[w][row][jl]      + zf[w][row][jl];
      float z_f = szp[w][row][8 + jl]  + zf[w][row][8 + jl];
      float z_c = szp[w][row][16 + jl] + zf[w][row][16 + jl];
      float z_o = szp[w][row][24 + jl] + zf[w][row][24 + jl];
      float iv = sigm(z_i + cp * wci + vbi);
      float fv = sigm(z_f + cp * wcf + vbf);
      float cn = fv * cp + iv * tanh_(z_c + vbc);
      float ov = sigm(z_o + cn * wco + vbo);
      float hn = ov * tanh_(cn);
      h16 hh = (h16)hn;
      unsigned hbits = ((unsigned)*(unsigned short*)&hh & 0xFFFEu) | tagn;
      store_coh2(hdst + row * 8 + jl, hbits);
      if (pr){ cB = cn; hnB = hn; } else { cA = cn; hnA = hn; }
    }
    out[((size_t)bgA * Ss + gs) * Hh + jg] = hnA;
    out[((size_t)bgB * Ss + gs) * Hh + jg] = hnB;
    if (last && s == Tc - 1){
      hT[bgA * Hh + jg] = hnA; cT[bgA * Hh + jg] = cA;
      hT[bgB * Hh + jg] = hnB; cT[bgB * Hh + jg] = cB;
    }

    zc0 = zn0; zc1 = zn1;
  }

  c_state[bgA * Hh + jg] = cA;
  c_state[bgB * Hh + jg] = cB;
}

// ---------------------------------------------------------------------------
extern "C" void kernel_launch(void* const* d_in, const int* in_sizes, int n_in,
                              void* d_out, int out_size, void* d_ws, size_t ws_size,
                              hipStream_t stream){
  const float* x   = (const float*)d_in[0];
  const float* h0  = (const float*)d_in[1];
  const float* c0  = (const float*)d_in[2];
  const float* Wxh = (const float*)d_in[3];
  const float* Wci = (const float*)d_in[4];
  const float* Wcf = (const float*)d_in[5];
  const float* Wco = (const float*)d_in[6];
  const float* bi  = (const float*)d_in[7];
  const float* bf  = (const float*)d_in[8];
  const float* bc  = (const float*)d_in[9];
  const float* bo  = (const float*)d_in[10];

  float* out = (float*)d_out;
  float* hT  = out + (size_t)Bb * Ss * Hh;
  float* cT  = hT + (size_t)Bb * Hh;

  uint8_t* ws = (uint8_t*)d_ws;
  size_t off = 0;
  auto take = [&](size_t bytes) -> uint8_t* {
    uint8_t* p = ws + off;
    off += (bytes + 255) & ~(size_t)255;
    return p;
  };
  h16*            WxT     = (h16*)take((size_t)G4 * Ii * 2);
  u32x4*          Wr      = (u32x4*)take((size_t)G4 * Hh * 2);
  unsigned short* hbuf    = (unsigned short*)take((size_t)4 * 2 * 8192 * 2);
  float*          c_state = (float*)take((size_t)Bb * Hh * 4);

  int Tc = Ss, tclog = 10;
  while (Tc > 2 && off + (size_t)Bb * Tc * G4 * 4 > ws_size){ Tc >>= 1; tclog--; }
  float* zxbuf = (float*)take((size_t)Bb * Tc * G4 * 4);

  prep_weights<<<(Ii * G4) / 256, 256, 0, stream>>>(Wxh, WxT);
  prep_rec<<<516, 256, 0, stream>>>(Wxh, Wr, h0, hbuf);

  int nch = Ss / Tc;
  for (int c = 0; c < nch; ++c){
    int t0 = c * Tc;
    dim3 grid(G4 / BN, Bb * Tc / BM);
    gemm_zx<<<grid, 256, 0, stream>>>(x, WxT, zxbuf, t0, tclog);
    lstm_rec2<<<NBK, 256, 0, stream>>>(zxbuf, Wr, hbuf, c0, c_state,
                                       Wci, Wcf, Wco, bi, bf, bc, bo,
                                       out, hT, cT, t0, Tc, c == 0, c == nch - 1);
  }
}